// Round 5
// baseline (269.768 us; speedup 1.0000x reference)
//
#include <hip/hip_runtime.h>
#include <math.h>

// Problem: x (B=2, C=64, T=16, H=128, W=128) fp32; w (1,2,7,7,7) fp32.
// out = sigmoid(conv3d(concat[max_c(x), mean_c(x)], w, pad=3)) * x
//
// R4 structure: 2 kernels (fused conv+sigmoid+mul). New vs R3:
//   - LDS tile stride 40 (16B-aligned rows) -> float4 ds_reads (3 per row
//     instead of 10 scalar b32): ~45% fewer LDS issue cycles in conv phase.
//   - incremental (no-divide) LDS fill indexing: kills ~1.2k VALU cyc/thread
//     of magic-mul address math.
//   K1 pool:      x (128 MiB) -> pmax|pavg (4 MiB)      [HBM-bound, ~22 us]
//   K2 conv+mul:  conv3d over pooled (LDS per-plane), attn kept in registers,
//                 out = attn * x with non-temporal stores (keep x L3-resident).

#define NP (2 * 16 * 128 * 128) // 524288 pooled points per channel

typedef float vfloat4 __attribute__((ext_vector_type(4))); // native vec: ok for nontemporal builtins

// ---------------- Kernel 1: channel max + mean pool (float4) ----------------
__global__ __launch_bounds__(256) void pool_kernel(const float* __restrict__ x,
                                                   float* __restrict__ pmax,
                                                   float* __restrict__ pavg) {
    int j = blockIdx.x * 256 + threadIdx.x; // float4 index in pooled space, [0, 131072)
    int b = j >> 16;                        // 65536 float4 per batch in pooled space
    int rest = j & 65535;
    const float4* x4 = (const float4*)x;
    int base = (b << 22) | rest;            // float4 index into x for c=0

    float4 v = x4[base];
    float4 vmax = v;
    float4 vsum = v;
#pragma unroll 8
    for (int c = 1; c < 64; ++c) {
        float4 u = x4[base + (c << 16)];
        vmax.x = fmaxf(vmax.x, u.x);
        vmax.y = fmaxf(vmax.y, u.y);
        vmax.z = fmaxf(vmax.z, u.z);
        vmax.w = fmaxf(vmax.w, u.w);
        vsum.x += u.x; vsum.y += u.y; vsum.z += u.z; vsum.w += u.w;
    }
    const float s = 1.0f / 64.0f;
    float4 vavg; vavg.x = vsum.x * s; vavg.y = vsum.y * s; vavg.z = vsum.z * s; vavg.w = vsum.w * s;
    ((float4*)pmax)[j] = vmax;
    ((float4*)pavg)[j] = vavg;
}

// -------- Kernel 2: 7x7x7 conv (2ch) + sigmoid + broadcast multiply ---------
// Block = 256 threads handles one (b, t) and a 32x32 (h,w) tile.
// LDS stages one dz-plane of the 2-channel pooled halo: 2 x 38 x 40 (stride 40
// keeps every (row, txg) base 16B-aligned for float4 ds_reads).
__global__ __launch_bounds__(256) void conv_mul_kernel(const float* __restrict__ pooled, // pmax | pavg contiguous
                                                       const float* __restrict__ wgt,    // (1,2,7,7,7)
                                                       const float* __restrict__ x,
                                                       float* __restrict__ out) {
    __shared__ float sm[2 * 38 * 40]; // 12160 B

    int bid = blockIdx.x;
    int tw0 = (bid & 3) << 5;
    int th0 = ((bid >> 2) & 3) << 5;
    int t = (bid >> 4) & 15;
    int b = bid >> 8;

    int tid = threadIdx.x;
    int ty = tid >> 3;         // 0..31 output row within tile
    int txg = (tid & 7) << 2;  // 0,4,...,28 output col group (4 consecutive w)

    // Phase-2 addressing, computed early so prefetch loads can issue now.
    // float4 index: b*2^22 + c*2^16 + t*2^12 + gh*2^5 + gw/4
    int base4 = (b << 22) + (t << 12) + ((th0 + ty) << 5) + ((tw0 + txg) >> 2);
    int cs = bid & 63; // per-block channel stagger
    const vfloat4* x4 = (const vfloat4*)x;
    vfloat4* o4 = (vfloat4*)out;

    // Prefetch first 8 staggered channels of x: loads fly during the conv
    // phase; data parks in VGPRs until the streaming phase.
    vfloat4 pre[8];
#pragma unroll
    for (int k = 0; k < 8; ++k)
        pre[k] = x4[base4 + (((cs + k) & 63) << 16)];

    // Fill-loop start coordinates (once; reset per plane).
    int ys = tid / 38;          // 0..6
    int xs = tid - ys * 38;     // 0..37

    float acc0 = 0.f, acc1 = 0.f, acc2 = 0.f, acc3 = 0.f;

    for (int dz = 0; dz < 7; ++dz) {
        int tsrc = t + dz - 3;
        if (tsrc < 0 || tsrc >= 16) continue; // block-uniform: barriers stay uniform

        __syncthreads(); // protect LDS from previous plane's readers
        {
            int planeBase = ((b << 4) + tsrc) << 14;
            int ch = 0, y = ys, xx = xs;
            for (int i = tid; i < 2 * 38 * 38; i += 256) {
                int gh = th0 + y - 3;
                int gw = tw0 + xx - 3;
                float val = 0.f;
                if ((unsigned)gh < 128u && (unsigned)gw < 128u)
                    val = pooled[ch * NP + planeBase + (gh << 7) + gw];
                sm[ch * 1520 + y * 40 + xx] = val;
                // advance by 256 slots in (ch, y, x) space: 256 = 6*38 + 28
                xx += 28; y += 6;
                if (xx >= 38) { xx -= 38; y += 1; }
                if (y >= 38)  { y -= 38; ch += 1; }
            }
        }
        __syncthreads();

        const float* wdz = wgt + dz * 49;
#pragma unroll
        for (int ch = 0; ch < 2; ++ch) {
#pragma unroll
            for (int dy = 0; dy < 7; ++dy) {
                const vfloat4* rp4 = (const vfloat4*)&sm[ch * 1520 + (ty + dy) * 40 + txg];
                vfloat4 r0 = rp4[0], r1 = rp4[1], r2 = rp4[2]; // 12 floats (need 10)
                float row[12] = {r0.x, r0.y, r0.z, r0.w,
                                 r1.x, r1.y, r1.z, r1.w,
                                 r2.x, r2.y, r2.z, r2.w};
                const float* wr = wdz + ch * 343 + dy * 7;
#pragma unroll
                for (int dx = 0; dx < 7; ++dx) {
                    float wv = wr[dx];
                    acc0 = fmaf(wv, row[dx + 0], acc0);
                    acc1 = fmaf(wv, row[dx + 1], acc1);
                    acc2 = fmaf(wv, row[dx + 2], acc2);
                    acc3 = fmaf(wv, row[dx + 3], acc3);
                }
            }
        }
    }

    vfloat4 av;
    av.x = 1.f / (1.f + __expf(-acc0));
    av.y = 1.f / (1.f + __expf(-acc1));
    av.z = 1.f / (1.f + __expf(-acc2));
    av.w = 1.f / (1.f + __expf(-acc3));

    // Phase 2: out[b, c, t, gh, gw..gw+3] = attn * x, for all 64 channels,
    // staggered start channel per block; non-temporal stores keep x in L3.
#pragma unroll
    for (int k = 0; k < 8; ++k) {
        int idx = base4 + (((cs + k) & 63) << 16);
        __builtin_nontemporal_store(pre[k] * av, &o4[idx]);
    }
#pragma unroll 8
    for (int k = 8; k < 64; ++k) {
        int idx = base4 + (((cs + k) & 63) << 16);
        vfloat4 xv = x4[idx];
        __builtin_nontemporal_store(xv * av, &o4[idx]);
    }
}

extern "C" void kernel_launch(void* const* d_in, const int* in_sizes, int n_in,
                              void* d_out, int out_size, void* d_ws, size_t ws_size,
                              hipStream_t stream) {
    const float* x = (const float*)d_in[0];
    const float* w = (const float*)d_in[1];
    float* out = (float*)d_out;
    float* ws = (float*)d_ws;

    float* pmax = ws;       // NP floats
    float* pavg = ws + NP;  // NP floats (must follow pmax: conv indexes ch*NP)

    pool_kernel<<<NP / 4 / 256, 256, 0, stream>>>(x, pmax, pavg);
    conv_mul_kernel<<<2 * 16 * 4 * 4, 256, 0, stream>>>(pmax, w, x, out);
}